// Round 3
// baseline (112.166 us; speedup 1.0000x reference)
//
#include <hip/hip_runtime.h>

#define Hn 128
#define Ln 2048
#define NBn 64
#define K 64          // chunk length
#define G 32          // chunks: G*K == Ln
#define PITCH 68      // 64+4: rows 16B-aligned for ds_read_b128; scan-phase
                      // writes stride 68 -> all 32 banks, 2 lanes/bank (free);
                      // b128 reduce: lane n quad = (17n)%8 = n%8, quad-distinct

// ---------------------------------------------------------------------------
// Phase 1: per-(h,chunk) local scan with s_in = 0.
//   y_local (incl. D*u) -> out;  chunk summary (A_c, b_c) -> ws.
//   A_c = (any reset in chunk) ? 0 : Lam^64;  b_c = local end state.
//   Reset is folded into the per-step Lam coefficient (computed off the
//   dependent chain), so the chain is exactly 2 fma deep per step.
// ---------------------------------------------------------------------------
__global__ __launch_bounds__(64) void phase1_local(
    const float* __restrict__ u,
    const float* __restrict__ Lre,  const float* __restrict__ Lim,
    const float* __restrict__ Bre,  const float* __restrict__ Bim,
    const float* __restrict__ Cre,  const float* __restrict__ Cim,
    const float* __restrict__ Dv,   const int* __restrict__ dflag,
    float* __restrict__ out,
    float* __restrict__ Acr, float* __restrict__ Aci,
    float* __restrict__ Bcr, float* __restrict__ Bci)
{
    __shared__ float g_s[K * PITCH];
    __shared__ float u_s[K];

    const int g = blockIdx.x, h = blockIdx.y, n = threadIdx.x;
    const int hn = h * NBn + n;
    const int l0 = g * K;

    const float lre = Lre[hn], lim = Lim[hn];
    const float bre = Bre[hn], bim = Bim[hn];
    const float c2re =  2.0f * Cre[hn];
    const float c2im = -2.0f * Cim[hn];
    const float Dh   = Dv[h];

    u_s[n] = u[h * Ln + l0 + n];
    const int dn = dflag[l0 + n];
    const unsigned long long m = __ballot(dn != 0);
    __syncthreads();

    float zre = 0.f, zim = 0.f;
    #pragma unroll
    for (int k = 0; k < K; ++k) {
        const bool  rs  = (m >> k) & 1ull;
        const float ul  = u_s[k];
        const float lrk = rs ? 0.f : lre;   // off-chain select
        const float lik = rs ? 0.f : lim;
        const float bur = bre * ul;
        const float bui = bim * ul;
        const float nr = fmaf(lrk, zre, fmaf(-lik, zim, bur));
        const float ni = fmaf(lrk, zim, fmaf( lik, zre, bui));
        zre = nr; zim = ni;
        g_s[k * PITCH + n] = fmaf(c2re, zre, c2im * zim);
    }
    __syncthreads();

    // lane t reduces over the 64 states for timestep l0+t via ds_read_b128
    const float4* row4 = reinterpret_cast<const float4*>(g_s + n * PITCH);
    float a0 = 0.f, a1 = 0.f, a2 = 0.f, a3 = 0.f;
    #pragma unroll
    for (int k = 0; k < NBn / 4; ++k) {
        const float4 v = row4[k];
        a0 += v.x; a1 += v.y; a2 += v.z; a3 += v.w;
    }
    out[h * Ln + l0 + n] = (a0 + a1) + (a2 + a3) + Dh * u_s[n];

    // chunk summary: Lam^64 via 6 squarings, zeroed if any reset in chunk
    float pr = lre, pi = lim;
    #pragma unroll
    for (int it = 0; it < 6; ++it) {
        const float sr2 = pr * pr - pi * pi;
        const float si2 = 2.f * pr * pi;
        pr = sr2; pi = si2;
    }
    if (m) { pr = 0.f; pi = 0.f; }
    const int idx = (h * G + g) * NBn + n;
    Acr[idx] = pr;  Aci[idx] = pi;
    Bcr[idx] = zre; Bci[idx] = zim;
}

// ---------------------------------------------------------------------------
// Fused phase 2+3: block (g,h) redundantly computes its own incoming state
// s_in(g) = combine of chunks 0..g-1 from x0 (<=31 chained complex FMAs,
// coalesced L2 loads), then applies the correction
//   y[l0+k] += 2*Re(sum_n C_n Lam_n^{k+1} s_in_n)   for k < first-reset.
// Lam-power chain split into two interleaved Lam^2 chains (half the depth).
// Block g==G-1 additionally emits the final state.
// ---------------------------------------------------------------------------
__global__ __launch_bounds__(64) void phase23_fixup(
    const float* __restrict__ x_re, const float* __restrict__ x_im,
    const float* __restrict__ Lre,  const float* __restrict__ Lim,
    const float* __restrict__ Cre,  const float* __restrict__ Cim,
    const int* __restrict__ dflag,
    const float* __restrict__ Acr,  const float* __restrict__ Aci,
    const float* __restrict__ Bcr,  const float* __restrict__ Bci,
    float* __restrict__ out)
{
    __shared__ float g_s[K * PITCH];

    const int g = blockIdx.x, h = blockIdx.y, n = threadIdx.x;
    const int hn = h * NBn + n;
    const int l0 = g * K;

    // ---- prefix combine: s_in for this chunk ----
    float sre = x_re[hn], sim = x_im[hn];
    for (int j = 0; j < g; ++j) {
        const int idx = (h * G + j) * NBn + n;
        const float ar = Acr[idx], ai = Aci[idx];
        const float br = Bcr[idx], bi = Bci[idx];
        const float nr = fmaf(ar, sre, fmaf(-ai, sim, br));
        const float ni = fmaf(ar, sim, fmaf( ai, sre, bi));
        sre = nr; sim = ni;
    }

    if (g == G - 1) {   // final state = own chunk applied to s_in
        const int idx = (h * G + g) * NBn + n;
        const float ar = Acr[idx], ai = Aci[idx];
        const float br = Bcr[idx], bi = Bci[idx];
        const float fr = fmaf(ar, sre, fmaf(-ai, sim, br));
        const float fi = fmaf(ar, sim, fmaf( ai, sre, bi));
        float* xlast = out + Hn * Ln;
        xlast[2 * hn + 0] = fr;
        xlast[2 * hn + 1] = fi;
    }

    // ---- correction term ----
    const float cr = Cre[hn], ci = Cim[hn];
    const float lre = Lre[hn], lim = Lim[hn];

    const int dn = dflag[l0 + n];
    const unsigned long long bal = __ballot(dn != 0);
    const int kr = bal ? (__ffsll(bal) - 1) : K;   // first reset local index

    const float pr = cr * sre - ci * sim;          // C * s_in
    const float pi = cr * sim + ci * sre;
    const float l2r = lre * lre - lim * lim;       // Lam^2
    const float l2i = 2.f * lre * lim;

    float tAr = fmaf(lre, pr, -lim * pi);          // k=0: C*s*Lam
    float tAi = fmaf(lre, pi,  lim * pr);
    float tBr = fmaf(l2r, pr, -l2i * pi);          // k=1: C*s*Lam^2
    float tBi = fmaf(l2r, pi,  l2i * pr);
    g_s[0 * PITCH + n] = tAr;
    g_s[1 * PITCH + n] = tBr;
    #pragma unroll
    for (int k = 2; k < K; k += 2) {
        const float nAr = fmaf(l2r, tAr, -l2i * tAi);
        const float nAi = fmaf(l2r, tAi,  l2i * tAr);
        tAr = nAr; tAi = nAi;
        g_s[k * PITCH + n] = tAr;
        const float nBr = fmaf(l2r, tBr, -l2i * tBi);
        const float nBi = fmaf(l2r, tBi,  l2i * tBr);
        tBr = nBr; tBi = nBi;
        g_s[(k + 1) * PITCH + n] = tBr;
    }
    __syncthreads();

    const float4* row4 = reinterpret_cast<const float4*>(g_s + n * PITCH);
    float a0 = 0.f, a1 = 0.f, a2 = 0.f, a3 = 0.f;
    #pragma unroll
    for (int k = 0; k < NBn / 4; ++k) {
        const float4 v = row4[k];
        a0 += v.x; a1 += v.y; a2 += v.z; a3 += v.w;
    }
    if (n < kr)
        out[h * Ln + l0 + n] += 2.f * ((a0 + a1) + (a2 + a3));
}

extern "C" void kernel_launch(void* const* d_in, const int* in_sizes, int n_in,
                              void* d_out, int out_size, void* d_ws, size_t ws_size,
                              hipStream_t stream) {
    const float* u    = (const float*)d_in[0];
    const float* x_re = (const float*)d_in[1];
    const float* x_im = (const float*)d_in[2];
    const float* Lre  = (const float*)d_in[3];
    const float* Lim  = (const float*)d_in[4];
    const float* Bre  = (const float*)d_in[5];
    const float* Bim  = (const float*)d_in[6];
    const float* Cre  = (const float*)d_in[7];
    const float* Cim  = (const float*)d_in[8];
    const float* Dv   = (const float*)d_in[9];
    const int*   dfl  = (const int*)d_in[10];
    float* out = (float*)d_out;

    const int HGN = Hn * G * NBn;          // 262144 floats = 1 MB per buffer
    float* Acr = (float*)d_ws;
    float* Aci = Acr + HGN;
    float* Bcr = Aci + HGN;
    float* Bci = Bcr + HGN;

    dim3 grid(G, Hn);
    phase1_local<<<grid, 64, 0, stream>>>(u, Lre, Lim, Bre, Bim, Cre, Cim,
                                          Dv, dfl, out, Acr, Aci, Bcr, Bci);
    phase23_fixup<<<grid, 64, 0, stream>>>(x_re, x_im, Lre, Lim, Cre, Cim,
                                           dfl, Acr, Aci, Bcr, Bci, out);
}

// Round 4
// 93.254 us; speedup vs baseline: 1.2028x; 1.2028x over previous
//
#include <hip/hip_runtime.h>

#define Hn 128
#define Ln 2048
#define NBn 64
#define K 64          // chunk length
#define G 32          // chunks: G*K == Ln
#define PITCH 68      // 64+4: rows 16B-aligned for ds_read_b128; scan-phase
                      // writes stride 1 across lanes -> 2 lanes/bank (free)

// ws layout:
//   Sum[(h*G+g)*NBn+n] : float4 {a_re, a_im, b_re, b_im}   (4 MB)
//   Sin[(h*G+g)*NBn+n] : float2 {s_in_re, s_in_im}         (2 MB)

// ---------------------------------------------------------------------------
// Phase 1: per-(h,chunk) local scan with s_in = 0.
//   y_local (incl. D*u) -> out;  chunk summary float4 -> Sum.
//   A_c = (any reset in chunk) ? 0 : Lam^64;  b_c = local end state.
//   Reset folded into the per-step Lam coefficient (off the dependent chain):
//   chain is exactly 2 fma deep per step.
// ---------------------------------------------------------------------------
__global__ __launch_bounds__(64) void phase1_local(
    const float* __restrict__ u,
    const float* __restrict__ Lre,  const float* __restrict__ Lim,
    const float* __restrict__ Bre,  const float* __restrict__ Bim,
    const float* __restrict__ Cre,  const float* __restrict__ Cim,
    const float* __restrict__ Dv,   const int* __restrict__ dflag,
    float* __restrict__ out,
    float4* __restrict__ Sum)
{
    __shared__ float g_s[K * PITCH];
    __shared__ float u_s[K];

    const int g = blockIdx.x, h = blockIdx.y, n = threadIdx.x;
    const int hn = h * NBn + n;
    const int l0 = g * K;

    const float lre = Lre[hn], lim = Lim[hn];
    const float bre = Bre[hn], bim = Bim[hn];
    const float c2re =  2.0f * Cre[hn];
    const float c2im = -2.0f * Cim[hn];
    const float Dh   = Dv[h];

    u_s[n] = u[h * Ln + l0 + n];
    const int dn = dflag[l0 + n];
    const unsigned long long m = __ballot(dn != 0);
    __syncthreads();

    float zre = 0.f, zim = 0.f;
    #pragma unroll
    for (int k = 0; k < K; ++k) {
        const bool  rs  = (m >> k) & 1ull;   // wave-uniform (scalar) select
        const float ul  = u_s[k];
        const float lrk = rs ? 0.f : lre;
        const float lik = rs ? 0.f : lim;
        const float bur = bre * ul;
        const float bui = bim * ul;
        const float nr = fmaf(lrk, zre, fmaf(-lik, zim, bur));
        const float ni = fmaf(lrk, zim, fmaf( lik, zre, bui));
        zre = nr; zim = ni;
        g_s[k * PITCH + n] = fmaf(c2re, zre, c2im * zim);
    }
    __syncthreads();

    // lane t reduces over the 64 states for timestep l0+t via ds_read_b128
    const float4* row4 = reinterpret_cast<const float4*>(g_s + n * PITCH);
    float a0 = 0.f, a1 = 0.f, a2 = 0.f, a3 = 0.f;
    #pragma unroll
    for (int k = 0; k < NBn / 4; ++k) {
        const float4 v = row4[k];
        a0 += v.x; a1 += v.y; a2 += v.z; a3 += v.w;
    }
    out[h * Ln + l0 + n] = (a0 + a1) + (a2 + a3) + Dh * u_s[n];

    // chunk summary: Lam^64 via 6 squarings, zeroed if any reset in chunk
    float pr = lre, pi = lim;
    #pragma unroll
    for (int it = 0; it < 6; ++it) {
        const float sr2 = pr * pr - pi * pi;
        const float si2 = 2.f * pr * pi;
        pr = sr2; pi = si2;
    }
    if (m) { pr = 0.f; pi = 0.f; }
    Sum[(h * G + g) * NBn + n] = make_float4(pr, pi, zre, zim);
}

// ---------------------------------------------------------------------------
// Phase 2: per-head serial combine over chunks (one dwordx4 load per step,
// unrolled so loads pipeline ahead of the 8-cyc FMA chain); writes each
// chunk's INCOMING state to Sin (float2) and the final state to out.
// ---------------------------------------------------------------------------
__global__ __launch_bounds__(64) void phase2_combine(
    const float* __restrict__ x_re, const float* __restrict__ x_im,
    const float4* __restrict__ Sum,
    float2* __restrict__ Sin,
    float* __restrict__ out)
{
    const int h = blockIdx.x, n = threadIdx.x;
    const int hn = h * NBn + n;
    float sre = x_re[hn], sim = x_im[hn];
    #pragma unroll
    for (int g = 0; g < G; ++g) {
        const int idx = (h * G + g) * NBn + n;
        const float4 s = Sum[idx];
        Sin[idx] = make_float2(sre, sim);
        const float nr = fmaf(s.x, sre, fmaf(-s.y, sim, s.z));
        const float ni = fmaf(s.x, sim, fmaf( s.y, sre, s.w));
        sre = nr; sim = ni;
    }
    float* xlast = out + Hn * Ln;
    xlast[2 * hn + 0] = sre;
    xlast[2 * hn + 1] = sim;
}

// ---------------------------------------------------------------------------
// Phase 3: per-(h,chunk) correction: y[l0+k] += 2*Re(sum_n C_n Lam_n^{k+1} s_in_n)
// masked to zero from the first reset in the chunk onward. Lam-power chain is
// split into two interleaved Lam^2 chains (half the dependent depth).
// ---------------------------------------------------------------------------
__global__ __launch_bounds__(64) void phase3_fixup(
    const float* __restrict__ Lre, const float* __restrict__ Lim,
    const float* __restrict__ Cre, const float* __restrict__ Cim,
    const int* __restrict__ dflag,
    const float2* __restrict__ Sin,
    float* __restrict__ out)
{
    __shared__ float g_s[K * PITCH];

    const int g = blockIdx.x, h = blockIdx.y, n = threadIdx.x;
    const int hn = h * NBn + n;
    const int l0 = g * K;
    const int idx = (h * G + g) * NBn + n;

    const float2 s = Sin[idx];
    const float cr = Cre[hn],  ci = Cim[hn];
    const float lre = Lre[hn], lim = Lim[hn];

    const int dn = dflag[l0 + n];
    const unsigned long long bal = __ballot(dn != 0);
    const int kr = bal ? (__ffsll(bal) - 1) : K;   // first reset local index

    const float pr = cr * s.x - ci * s.y;          // C * s_in
    const float pi = cr * s.y + ci * s.x;
    const float l2r = lre * lre - lim * lim;       // Lam^2
    const float l2i = 2.f * lre * lim;

    float tAr = fmaf(lre, pr, -lim * pi);          // k=0: C*s*Lam
    float tAi = fmaf(lre, pi,  lim * pr);
    float tBr = fmaf(l2r, pr, -l2i * pi);          // k=1: C*s*Lam^2
    float tBi = fmaf(l2r, pi,  l2i * pr);
    g_s[0 * PITCH + n] = tAr;
    g_s[1 * PITCH + n] = tBr;
    #pragma unroll
    for (int k = 2; k < K; k += 2) {
        const float nAr = fmaf(l2r, tAr, -l2i * tAi);
        const float nAi = fmaf(l2r, tAi,  l2i * tAr);
        tAr = nAr; tAi = nAi;
        g_s[k * PITCH + n] = tAr;
        const float nBr = fmaf(l2r, tBr, -l2i * tBi);
        const float nBi = fmaf(l2r, tBi,  l2i * tBr);
        tBr = nBr; tBi = nBi;
        g_s[(k + 1) * PITCH + n] = tBr;
    }
    __syncthreads();

    const float4* row4 = reinterpret_cast<const float4*>(g_s + n * PITCH);
    float a0 = 0.f, a1 = 0.f, a2 = 0.f, a3 = 0.f;
    #pragma unroll
    for (int k = 0; k < NBn / 4; ++k) {
        const float4 v = row4[k];
        a0 += v.x; a1 += v.y; a2 += v.z; a3 += v.w;
    }
    if (n < kr)
        out[h * Ln + l0 + n] += 2.f * ((a0 + a1) + (a2 + a3));
}

extern "C" void kernel_launch(void* const* d_in, const int* in_sizes, int n_in,
                              void* d_out, int out_size, void* d_ws, size_t ws_size,
                              hipStream_t stream) {
    const float* u    = (const float*)d_in[0];
    const float* x_re = (const float*)d_in[1];
    const float* x_im = (const float*)d_in[2];
    const float* Lre  = (const float*)d_in[3];
    const float* Lim  = (const float*)d_in[4];
    const float* Bre  = (const float*)d_in[5];
    const float* Bim  = (const float*)d_in[6];
    const float* Cre  = (const float*)d_in[7];
    const float* Cim  = (const float*)d_in[8];
    const float* Dv   = (const float*)d_in[9];
    const int*   dfl  = (const int*)d_in[10];
    float* out = (float*)d_out;

    const int HGN = Hn * G * NBn;          // 262144 entries
    float4* Sum = (float4*)d_ws;           // 4 MB
    float2* Sin = (float2*)(Sum + HGN);    // 2 MB

    dim3 grid(G, Hn);
    phase1_local<<<grid, 64, 0, stream>>>(u, Lre, Lim, Bre, Bim, Cre, Cim,
                                          Dv, dfl, out, Sum);
    phase2_combine<<<Hn, 64, 0, stream>>>(x_re, x_im, Sum, Sin, out);
    phase3_fixup<<<grid, 64, 0, stream>>>(Lre, Lim, Cre, Cim, dfl, Sin, out);
}

// Round 5
// 92.095 us; speedup vs baseline: 1.2179x; 1.0126x over previous
//
#include <hip/hip_runtime.h>

#define Hn 128
#define Ln 2048
#define NBn 64
#define K 64          // chunk length
#define G 32          // chunks per head
#define W 8           // waves per block
#define CPW 4         // chunks per wave
#define PITCH 68      // 64+4: rows 16B-aligned for ds_read_b128; 2-way bank
                      // aliasing on scan writes (free per m136)

// Single fused kernel: block = head. Wave w owns chunks 4w..4w+3.
// Everything runs in "w-space": w' = 2*C*z (same diagonal recurrence,
// input coefficient 2*C*B). y_t = sum_n Re(w'_n) + D*u; final state
// z = w'/(2C) (one complex divide at the very end).
__global__ __launch_bounds__(512) void ssm_fused(
    const float* __restrict__ u,
    const float* __restrict__ x_re, const float* __restrict__ x_im,
    const float* __restrict__ Lre,  const float* __restrict__ Lim,
    const float* __restrict__ Bre,  const float* __restrict__ Bim,
    const float* __restrict__ Cre,  const float* __restrict__ Cim,
    const float* __restrict__ Dv,   const int* __restrict__ dflag,
    float* __restrict__ out)
{
    __shared__ float  g_s[W][K * PITCH];   // per-wave transpose buffer (139 KB)
    __shared__ float2 b_s[G][NBn];         // w-space chunk end states (16 KB)
    __shared__ int    f_s[G];              // chunk-has-reset flags

    const int h   = blockIdx.x;
    const int tid = threadIdx.x;
    const int w   = tid >> 6;
    const int n   = tid & 63;
    const int hn  = h * NBn + n;

    const float lre = Lre[hn], lim = Lim[hn];
    const float cr  = Cre[hn], ci  = Cim[hn];
    const float br  = Bre[hn], bi  = Bim[hn];
    const float Dh  = Dv[h];
    const float cbr2 = 2.f * (cr * br - ci * bi);   // 2*C*B
    const float cbi2 = 2.f * (cr * bi + ci * br);

    // Lam^64 via 6 squarings (off critical path)
    float l64r = lre, l64i = lim;
    #pragma unroll
    for (int it = 0; it < 6; ++it) {
        const float a  = l64r * l64r - l64i * l64i;
        const float b2 = 2.f * l64r * l64i;
        l64r = a; l64i = b2;
    }

    float ybase[CPW];
    unsigned long long mask[CPW];
    float* gbuf = g_s[w];

    // ---------------- Stage A: local chunk scans (s_in = 0) ----------------
    #pragma unroll
    for (int j = 0; j < CPW; ++j) {
        const int g  = w * CPW + j;
        const int l0 = g * K;
        const float ul = u[h * Ln + l0 + n];
        const int   dn = dflag[l0 + n];
        const unsigned long long m = __ballot(dn != 0);
        mask[j] = m;
        // stage own u into the pad columns of row 0? no — dedicated LDS read
        // path: reuse gbuf pad is messy; use a wave-synchronous staging row.
        // Wave-private LDS: same-wave ds_write then ds_read is ordered (DS
        // pipe is in-order per wave) — no barrier needed.
        gbuf[64] = 0.f; // (keep pad deterministic; not strictly needed)
        __shared__ float u_s[W][K];
        u_s[w][n] = ul;

        float wr = 0.f, wi = 0.f;
        if (m == 0ull) {
            #pragma unroll
            for (int k = 0; k < K; ++k) {
                const float uk = u_s[w][k];
                const float nr = fmaf(lre, wr, fmaf(-lim, wi, cbr2 * uk));
                const float ni = fmaf(lre, wi, fmaf( lim, wr, cbi2 * uk));
                wr = nr; wi = ni;
                gbuf[k * PITCH + n] = wr;
            }
        } else {
            #pragma unroll
            for (int k = 0; k < K; ++k) {
                const bool  rs  = (m >> k) & 1ull;
                const float lrk = rs ? 0.f : lre;
                const float lik = rs ? 0.f : lim;
                const float uk  = u_s[w][k];
                const float nr = fmaf(lrk, wr, fmaf(-lik, wi, cbr2 * uk));
                const float ni = fmaf(lrk, wi, fmaf( lik, wr, cbi2 * uk));
                wr = nr; wi = ni;
                gbuf[k * PITCH + n] = wr;
            }
        }
        b_s[g][n] = make_float2(wr, wi);
        if (n == 0) f_s[g] = (m != 0ull) ? 1 : 0;

        // transpose-reduce: lane t sums row t (timestep l0+t) via ds_read_b128
        const float4* row4 = reinterpret_cast<const float4*>(gbuf + n * PITCH);
        float a0 = 0.f, a1 = 0.f, a2 = 0.f, a3 = 0.f;
        #pragma unroll
        for (int k2 = 0; k2 < K / 4; ++k2) {
            const float4 v = row4[k2];
            a0 += v.x; a1 += v.y; a2 += v.z; a3 += v.w;
        }
        ybase[j] = (a0 + a1) + (a2 + a3) + Dh * ul;
    }
    __syncthreads();

    // ------------- Stage B: redundant serial combine over chunks -----------
    const float x0r = x_re[hn], x0i = x_im[hn];
    float sr = 2.f * (cr * x0r - ci * x0i);     // w-space initial state
    float si = 2.f * (cr * x0i + ci * x0r);
    float sinr[CPW], sini[CPW];
    #pragma unroll
    for (int g = 0; g < G; ++g) {
        if ((g >> 2) == w) { sinr[g & 3] = sr; sini[g & 3] = si; }
        const float2 b  = b_s[g][n];
        const bool  rst = f_s[g] != 0;
        const float ar  = rst ? 0.f : l64r;
        const float ai  = rst ? 0.f : l64i;
        const float nr = fmaf(ar, sr, fmaf(-ai, si, b.x));
        const float ni = fmaf(ar, si, fmaf( ai, sr, b.y));
        sr = nr; si = ni;
    }
    if (w == W - 1) {   // final state: z = w'/(2C), interleaved complex64
        const float c2r = 2.f * cr, c2i = 2.f * ci;
        const float inv = 1.f / (c2r * c2r + c2i * c2i);
        float* xlast = out + Hn * Ln;
        xlast[2 * hn + 0] = (sr * c2r + si * c2i) * inv;
        xlast[2 * hn + 1] = (si * c2r - sr * c2i) * inv;
    }

    // ------------- Stage C: correction + single y store --------------------
    const float l2r = lre * lre - lim * lim;    // Lam^2
    const float l2i = 2.f * lre * lim;
    #pragma unroll
    for (int j = 0; j < CPW; ++j) {
        const int g  = w * CPW + j;
        const int l0 = g * K;
        const unsigned long long m = mask[j];
        const int kr = m ? (__ffsll((long long)m) - 1) : K;

        const float pr = sinr[j], pi = sini[j];
        float tAr = fmaf(lre, pr, -lim * pi);   // w_in * Lam
        float tAi = fmaf(lre, pi,  lim * pr);
        float tBr = fmaf(l2r, pr, -l2i * pi);   // w_in * Lam^2
        float tBi = fmaf(l2r, pi,  l2i * pr);
        gbuf[0 * PITCH + n] = tAr;
        gbuf[1 * PITCH + n] = tBr;
        #pragma unroll
        for (int k = 2; k < K; k += 2) {
            const float nAr = fmaf(l2r, tAr, -l2i * tAi);
            const float nAi = fmaf(l2r, tAi,  l2i * tAr);
            tAr = nAr; tAi = nAi;
            gbuf[k * PITCH + n] = tAr;
            const float nBr = fmaf(l2r, tBr, -l2i * tBi);
            const float nBi = fmaf(l2r, tBi,  l2i * tBr);
            tBr = nBr; tBi = nBi;
            gbuf[(k + 1) * PITCH + n] = tBr;
        }
        const float4* row4 = reinterpret_cast<const float4*>(gbuf + n * PITCH);
        float a0 = 0.f, a1 = 0.f, a2 = 0.f, a3 = 0.f;
        #pragma unroll
        for (int k2 = 0; k2 < K / 4; ++k2) {
            const float4 v = row4[k2];
            a0 += v.x; a1 += v.y; a2 += v.z; a3 += v.w;
        }
        const float corr = (n < kr) ? ((a0 + a1) + (a2 + a3)) : 0.f;
        out[h * Ln + l0 + n] = ybase[j] + corr;   // single coalesced store
    }
}

extern "C" void kernel_launch(void* const* d_in, const int* in_sizes, int n_in,
                              void* d_out, int out_size, void* d_ws, size_t ws_size,
                              hipStream_t stream) {
    const float* u    = (const float*)d_in[0];
    const float* x_re = (const float*)d_in[1];
    const float* x_im = (const float*)d_in[2];
    const float* Lre  = (const float*)d_in[3];
    const float* Lim  = (const float*)d_in[4];
    const float* Bre  = (const float*)d_in[5];
    const float* Bim  = (const float*)d_in[6];
    const float* Cre  = (const float*)d_in[7];
    const float* Cim  = (const float*)d_in[8];
    const float* Dv   = (const float*)d_in[9];
    const int*   dfl  = (const int*)d_in[10];
    float* out = (float*)d_out;

    ssm_fused<<<Hn, W * 64, 0, stream>>>(u, x_re, x_im, Lre, Lim,
                                         Bre, Bim, Cre, Cim, Dv, dfl, out);
}